// Round 2
// 165.810 us; speedup vs baseline: 1.0456x; 1.0456x over previous
//
#include <hip/hip_runtime.h>

// GQA prefill block, MI355X gfx950. Round 16: fixes round-15's NaN (host-side
// in_sizes dtype detect was wrong -- in_sizes is element count, so fp32 input
// was read as bf16). Dtype detect is back on-device (cos[0] probe) inside an
// unconditional convert/copy pass: x -> bf16 aliased into `at` (free until
// flash), wq/wk/wv -> bf16 into d_out (free until gemm_o overwrites it).
// Workspace usage stays at 20 MB. GEMMs keep round-15 structure: 128m x 64n,
// BK=64, acc[2][4], all staging via global_load_lds width-16 (proj pure-bf16;
// gemm_o's W stays dtype-dual stage_rows). proj grid 768 = 3 blocks/CU,
// oproj grid 512 = 2/CU. Flash v7 unchanged.
// 4 dispatches: convert | proj | flash | oproj.

typedef __bf16 bf16;
typedef __attribute__((ext_vector_type(8))) __bf16 bf16x8;
typedef __attribute__((ext_vector_type(4))) float f32x4;

#define MFMA(a, b, c) __builtin_amdgcn_mfma_f32_16x16x32_bf16((a), (b), (c), 0, 0, 0)
#define GLOAD_LDS16(g, l)                                        \
  __builtin_amdgcn_global_load_lds(                              \
      (const __attribute__((address_space(1))) void*)(g),        \
      (__attribute__((address_space(3))) void*)(l), 16, 0, 0)

__device__ __forceinline__ bool is_bf16_input(const void* cosRaw) {
  return ((const unsigned short*)cosRaw)[0] == 0x3F80;  // cos(0)=1.0 bf16
}
__device__ __forceinline__ float rdval(const void* p, int idx, bool isbf) {
  return isbf ? (float)((const bf16*)p)[idx] : ((const float*)p)[idx];
}

// stage one 8-row group (8 rows x 64 cols bf16) into LDS at ls[0..511]
// (+lane*16B by HW for bf16 path), XOR-swizzled chunks. Used by gemm_o's
// dtype-dual W staging only.
__device__ __forceinline__ void stage_rows(const void* src, size_t rowbase,
                                           int ko, int srow, int csrc,
                                           int lane, bf16* ls, bool isbf) {
  if (isbf) {
    GLOAD_LDS16(&((const bf16*)src)[(rowbase + srow) * 1024 + ko + csrc * 8], ls);
  } else {
    const float* fp = &((const float*)src)[(rowbase + srow) * 1024 + ko + csrc * 8];
    float4 f0 = *(const float4*)fp;
    float4 f1 = *(const float4*)(fp + 4);
    bf16x8 o;
    o[0] = (bf16)f0.x; o[1] = (bf16)f0.y; o[2] = (bf16)f0.z; o[3] = (bf16)f0.w;
    o[4] = (bf16)f1.x; o[5] = (bf16)f1.y; o[6] = (bf16)f1.z; o[7] = (bf16)f1.w;
    *(bf16x8*)&ls[lane * 8] = o;
  }
}

// ---------------------------------------------------------------------------
// Unconditional convert/copy -> bf16. Device-side dtype detect via cos table.
// x (4194304 elems) -> dx; wq|wk|wv (1572864 elems) -> dw contiguous.
// 8 elems/thread; chunk boundaries (8-elem units):
// x 524288 | wq 131072 | wk 32768 | wv 32768  (total 720896 = 2816 x 256).
// Weight dst chunk = c - 524288 (src and dst both contiguous in that order).
// ---------------------------------------------------------------------------
__global__ __launch_bounds__(256) void convert_kernel(
    const void* __restrict__ x, const void* __restrict__ wq,
    const void* __restrict__ wk, const void* __restrict__ wv,
    bf16* __restrict__ dx, bf16* __restrict__ dw,
    const void* __restrict__ cosraw) {
  const bool isbf = is_bf16_input(cosraw);
  const int c = (int)blockIdx.x * 256 + (int)threadIdx.x;  // 0..720895
  const void* src;
  int off;
  bf16* dst;
  int dc;
  if (c < 524288)      { src = x;  off = c;          dst = dx; dc = c; }
  else if (c < 655360) { src = wq; off = c - 524288; dst = dw; dc = c - 524288; }
  else if (c < 688128) { src = wk; off = c - 655360; dst = dw; dc = c - 524288; }
  else                 { src = wv; off = c - 688128; dst = dw; dc = c - 524288; }
  bf16x8 o;
  if (isbf) {
    o = ((const bf16x8*)src)[off];
  } else {
    const float4* fp = (const float4*)src + (size_t)off * 2;
    float4 f0 = fp[0];
    float4 f1 = fp[1];
    o[0] = (bf16)f0.x; o[1] = (bf16)f0.y; o[2] = (bf16)f0.z; o[3] = (bf16)f0.w;
    o[4] = (bf16)f1.x; o[5] = (bf16)f1.y; o[6] = (bf16)f1.z; o[7] = (bf16)f1.w;
  }
  ((bf16x8*)dst)[dc] = o;
}

// ---------------------------------------------------------------------------
// Fused q/k/v projection. 128m x 64n tile, BK=64, single-buffered 24 KB LDS,
// grid 768 = 3 blocks/CU uniform. All staging via global_load_lds (bf16
// sources). XOR-swizzled LDS (inverse-swizzle on global source, swizzle on
// ds_read). nb 0..15 q (norm+rope+1/8 -> qp), 16..19 k (norm+rope -> kp),
// 20..23 v (block LDS transpose -> vt (B,KV,64,T)).
// ---------------------------------------------------------------------------
__global__ __launch_bounds__(256, 3) void proj_kernel(
    const bf16* __restrict__ xb, const bf16* __restrict__ wqb,
    const bf16* __restrict__ wkb, const bf16* __restrict__ wvb,
    bf16* __restrict__ qp, bf16* __restrict__ kp, bf16* __restrict__ vt,
    const void* __restrict__ cosraw, const void* __restrict__ sinraw,
    const void* __restrict__ qnraw, const void* __restrict__ knraw) {
  __shared__ bf16 As[128 * 64];  // 16 KB
  __shared__ bf16 Bs[64 * 64];   //  8 KB

  const int idx = (int)blockIdx.x;       // 0..767
  const int xcd = idx & 7;
  const int jj = idx >> 3;               // 0..95
  const int mb = (jj & 3) * 8 + xcd;     // 0..31
  const int nb = jj >> 2;                // 0..23
  const int n0 = nb * 64;
  const int m0 = mb * 128;

  const int tid = threadIdx.x;
  const int wave = tid >> 6;
  const int lane = tid & 63;
  const int q16 = lane & 15;
  const int quad = lane >> 4;
  const int srow = lane >> 3;
  const int csrc = (lane & 7) ^ srow;
  const int x7 = q16 & 7;

  const bf16* wsrc;
  int nr0;
  if (nb < 16)      { wsrc = wqb; nr0 = n0; }
  else if (nb < 20) { wsrc = wkb; nr0 = n0 - 1024; }
  else              { wsrc = wvb; nr0 = n0 - 1280; }

  f32x4 acc[2][4];
#pragma unroll
  for (int mf = 0; mf < 2; ++mf)
#pragma unroll
    for (int nt = 0; nt < 4; ++nt) acc[mf][nt] = (f32x4){0.f, 0.f, 0.f, 0.f};

  for (int kt = 0; kt < 16; ++kt) {
    const int ko = kt * 64;
#pragma unroll
    for (int i = 0; i < 4; ++i) {
      int rb = wave * 32 + i * 8;
      GLOAD_LDS16(&xb[(size_t)(m0 + rb + srow) * 1024 + ko + csrc * 8],
                  &As[rb * 64]);
    }
#pragma unroll
    for (int i = 0; i < 2; ++i) {
      int rb = wave * 16 + i * 8;
      GLOAD_LDS16(&wsrc[(size_t)(nr0 + rb + srow) * 1024 + ko + csrc * 8],
                  &Bs[rb * 64]);
    }
    __syncthreads();

    bf16x8 a[2][2], bfr[4][2];
#pragma unroll
    for (int mf = 0; mf < 2; ++mf) {
      const bf16* rp = &As[(wave * 32 + mf * 16 + q16) * 64];
      a[mf][0] = *(const bf16x8*)&rp[(quad ^ x7) * 8];
      a[mf][1] = *(const bf16x8*)&rp[((quad + 4) ^ x7) * 8];
    }
#pragma unroll
    for (int nt = 0; nt < 4; ++nt) {
      const bf16* rp = &Bs[(nt * 16 + q16) * 64];
      bfr[nt][0] = *(const bf16x8*)&rp[(quad ^ x7) * 8];
      bfr[nt][1] = *(const bf16x8*)&rp[((quad + 4) ^ x7) * 8];
    }
#pragma unroll
    for (int nt = 0; nt < 4; ++nt)
#pragma unroll
      for (int mf = 0; mf < 2; ++mf) {
        acc[mf][nt] = MFMA(a[mf][0], bfr[nt][0], acc[mf][nt]);
        acc[mf][nt] = MFMA(a[mf][1], bfr[nt][1], acc[mf][nt]);
      }
    __syncthreads();
  }

  if (nb < 20) {
    const bool isbf = is_bf16_input(cosraw);
    const void* nwp = (nb < 16) ? qnraw : knraw;
    const float osc = (nb < 16) ? 0.125f : 1.0f;
    float wd[4];
#pragma unroll
    for (int nt = 0; nt < 4; ++nt) wd[nt] = rdval(nwp, nt * 16 + q16, isbf);

#pragma unroll
    for (int mf = 0; mf < 2; ++mf) {
#pragma unroll
      for (int r = 0; r < 4; ++r) {
        float p = acc[mf][0][r] * acc[mf][0][r] + acc[mf][1][r] * acc[mf][1][r] +
                  acc[mf][2][r] * acc[mf][2][r] + acc[mf][3][r] * acc[mf][3][r];
#pragma unroll
        for (int off = 8; off >= 1; off >>= 1) p += __shfl_xor(p, off);
        float rms = rsqrtf(p * (1.0f / 64.0f) + 1e-6f);

        int row = m0 + wave * 32 + mf * 16 + quad * 4 + r;
        int t = row & 2047;
        float c0 = rdval(cosraw, t * 32 + q16, isbf);
        float c1 = rdval(cosraw, t * 32 + 16 + q16, isbf);
        float s0 = rdval(sinraw, t * 32 + q16, isbf);
        float s1 = rdval(sinraw, t * 32 + 16 + q16, isbf);

        float v0 = acc[mf][0][r] * rms * wd[0];
        float v1 = acc[mf][1][r] * rms * wd[1];
        float v2 = acc[mf][2][r] * rms * wd[2];
        float v3 = acc[mf][3][r] * rms * wd[3];

        bf16* op = (nb < 16) ? &qp[(size_t)row * 1024 + nb * 64]
                             : &kp[(size_t)row * 256 + (nb - 16) * 64];
        op[0 * 16 + q16] = (bf16)((v0 * c0 - v2 * s0) * osc);
        op[1 * 16 + q16] = (bf16)((v1 * c1 - v3 * s1) * osc);
        op[2 * 16 + q16] = (bf16)((v2 * c0 + v0 * s0) * osc);
        op[3 * 16 + q16] = (bf16)((v3 * c1 + v1 * s1) * osc);
      }
    }
  } else {
    const int vh = nb - 20;
    const int b = m0 >> 11;
    const int tbase = m0 & 2047;
#pragma unroll
    for (int mf = 0; mf < 2; ++mf)
#pragma unroll
      for (int nt = 0; nt < 4; ++nt)
#pragma unroll
        for (int r = 0; r < 4; ++r)
          As[(wave * 32 + mf * 16 + quad * 4 + r) * 64 + nt * 16 + q16] =
              (bf16)acc[mf][nt][r];
    __syncthreads();
#pragma unroll
    for (int rep = 0; rep < 4; ++rep) {
      int c = tid + 256 * rep;      // 0..1023
      int d = c >> 4;               // 0..63
      int t8 = (c & 15) * 8;        // 0..120
      bf16x8 pk;
#pragma unroll
      for (int j = 0; j < 8; ++j) pk[j] = As[(t8 + j) * 64 + d];
      *(bf16x8*)&vt[(((size_t)(b * 4 + vh)) * 64 + d) * 2048 + tbase + t8] = pk;
    }
  }
}

// ---------------------------------------------------------------------------
// Flash attention v7 (unchanged): 1 head/block, grid (32,16,2) = 1024 =
// 4 blocks/CU. LDS 36 KB: K/V dbuf (16+16) + per-wave 16x32 kh-sequential P
// scratch (4). Fixed-max softmax exp(S-9); l via ones-MFMA. qblk pairing ->
// co-resident blocks per CU sum to exactly 66 tile-units.
// ---------------------------------------------------------------------------
__global__ __launch_bounds__(256, 4) void flash_kernel(
    const bf16* __restrict__ qp, const bf16* __restrict__ kp,
    const bf16* __restrict__ vt, bf16* __restrict__ attn) {
  const int qblk = blockIdx.z ? 31 - (int)blockIdx.x : (int)blockIdx.x;
  const int h = blockIdx.y;
  const int b = blockIdx.z;
  const int kvh = h >> 2;
  const int tid = threadIdx.x;
  const int wave = tid >> 6;
  const int lane = tid & 63;
  const int q16 = lane & 15;
  const int quad = lane >> 4;
  const int r7 = q16 & 7;
  const int t0 = qblk * 64 + wave * 16;

  __shared__ bf16 Ks[2][64 * 64];   // 16 KB
  __shared__ bf16 Vs[2][64 * 64];   // 16 KB
  __shared__ bf16 Pl[4][16 * 32];   //  4 KB, per-wave, kh-sequential

  const bf16* qrow = qp + (((size_t)(b * 2048 + t0 + q16)) * 16 + h) * 64;
  bf16x8 qa0 = *(const bf16x8*)(qrow + quad * 8);
  bf16x8 qa1 = *(const bf16x8*)(qrow + 32 + quad * 8);

  bf16x8 ones;
#pragma unroll
  for (int j = 0; j < 8; ++j) ones[j] = (bf16)1.0f;

  f32x4 O[4], l4;
#pragma unroll
  for (int nt = 0; nt < 4; ++nt) O[nt] = (f32x4){0.f, 0.f, 0.f, 0.f};
  l4 = (f32x4){0.f, 0.f, 0.f, 0.f};

  const int ntile = qblk + 1;

  bf16x8 kr[2], vr[2];
  const int cr = tid * 2;
  const int krow = cr >> 3;
  const size_t kgbase = (((size_t)(b * 2048) + krow) * 4 + kvh) * 64;
  const size_t vgbase = ((size_t)(b * 4 + kvh) * 64 + krow) * 2048;

  auto gload = [&](int tk) {
#pragma unroll
    for (int rep = 0; rep < 2; ++rep) {
      int ch = (cr + rep) & 7;
      kr[rep] = *(const bf16x8*)&kp[kgbase + (size_t)(tk * 64) * 256 + ch * 8];
      vr[rep] = *(const bf16x8*)&vt[vgbase + tk * 64 + ch * 8];
    }
  };
  auto swrite = [&](int bb) {
#pragma unroll
    for (int rep = 0; rep < 2; ++rep) {
      int ch = (cr + rep) & 7;
      int pos = (ch ^ (krow & 7)) * 8;
      *(bf16x8*)&Ks[bb][krow * 64 + pos] = kr[rep];
      *(bf16x8*)&Vs[bb][krow * 64 + pos] = vr[rep];
    }
  };

  gload(0);

  for (int t = 0; t < ntile; ++t) {
    const int bb = t & 1;
    const int kbase = t * 64;
    swrite(bb);
    __syncthreads();
    if (t + 1 < ntile) gload(t + 1);

    // S = Q K^T over 4 key subtiles of 16
    f32x4 s[4];
#pragma unroll
    for (int kt = 0; kt < 4; ++kt) {
      const bf16* kr0 = &Ks[bb][(kt * 16 + q16) * 64];
      bf16x8 kb0 = *(const bf16x8*)&kr0[(quad ^ r7) * 8];
      bf16x8 kb1 = *(const bf16x8*)&kr0[((quad + 4) ^ r7) * 8];
      f32x4 z = (f32x4){0.f, 0.f, 0.f, 0.f};
      z = MFMA(qa0, kb0, z);
      z = MFMA(qa1, kb1, z);
      s[kt] = z;
    }

    if (kbase + 63 > t0) {
#pragma unroll
      for (int kt = 0; kt < 4; ++kt) {
        int jt = kbase + kt * 16 + q16;
#pragma unroll
        for (int r = 0; r < 4; ++r)
          if (jt > t0 + quad * 4 + r) s[kt][r] = -1e30f;
      }
    }

#pragma unroll
    for (int kt = 0; kt < 4; ++kt)
#pragma unroll
      for (int r = 0; r < 4; ++r) s[kt][r] = __expf(s[kt][r] - 9.0f);

    // kh-sequential P roundtrip (16x32 per-wave scratch) + PV
#pragma unroll
    for (int kh = 0; kh < 2; ++kh) {
#pragma unroll
      for (int ct = 0; ct < 2; ++ct) {
        const int kt = kh * 2 + ct;
#pragma unroll
        for (int r = 0; r < 4; ++r) {
          int row = quad * 4 + r;
          int col = ct * 16 + q16;                  // 0..31
          Pl[wave][row * 32 + (((col >> 3) ^ (row & 3)) * 8) + (col & 7)] =
              (bf16)s[kt][r];
        }
      }
      bf16x8 pa = *(const bf16x8*)&Pl[wave][q16 * 32 + ((quad ^ (q16 & 3)) * 8)];
#pragma unroll
      for (int nt = 0; nt < 4; ++nt) {
        const bf16* vr0 = &Vs[bb][(nt * 16 + q16) * 64];
        bf16x8 vb = *(const bf16x8*)&vr0[((kh * 4 + quad) ^ r7) * 8];
        O[nt] = MFMA(pa, vb, O[nt]);
      }
      l4 = MFMA(pa, ones, l4);
    }
  }

  float inv[4];
#pragma unroll
  for (int r = 0; r < 4; ++r) inv[r] = 1.0f / l4[r];
#pragma unroll
  for (int nt = 0; nt < 4; ++nt)
#pragma unroll
    for (int r = 0; r < 4; ++r) {
      size_t o = (((size_t)(b * 2048 + t0 + quad * 4 + r)) * 16 + h) * 64 +
                 nt * 16 + q16;
      attn[o] = (bf16)(O[nt][r] * inv[r]);
    }
}

// ---------------------------------------------------------------------------
// o-projection: 128m x 64n BK=64 single-buffered, grid 512 = 2 blocks/CU
// uniform, XCD swizzle. A (bf16) via global_load_lds; W dtype-dual via
// stage_rows. Output dtype per detected dtype.
// ---------------------------------------------------------------------------
__global__ __launch_bounds__(256, 2) void gemm_o_kernel(
    const bf16* __restrict__ A, const void* __restrict__ Wraw,
    void* __restrict__ C, const void* __restrict__ cosraw) {
  __shared__ bf16 As[128 * 64];  // 16 KB
  __shared__ bf16 Bs[64 * 64];   //  8 KB

  const int idx = (int)blockIdx.x;       // 0..511
  const int xcd = idx & 7;
  const int jj = idx >> 3;               // 0..63
  const int mb = (jj & 3) * 8 + xcd;     // 0..31
  const int nb = jj >> 2;                // 0..15
  const int n0 = nb * 64;
  const int m0 = mb * 128;

  const int tid = threadIdx.x;
  const int wave = tid >> 6;
  const int lane = tid & 63;
  const int q16 = lane & 15;
  const int quad = lane >> 4;
  const int srow = lane >> 3;
  const int csrc = (lane & 7) ^ srow;
  const int x7 = q16 & 7;
  const bool isbf = is_bf16_input(cosraw);

  f32x4 acc[2][4];
#pragma unroll
  for (int mf = 0; mf < 2; ++mf)
#pragma unroll
    for (int nt = 0; nt < 4; ++nt) acc[mf][nt] = (f32x4){0.f, 0.f, 0.f, 0.f};

  for (int kt = 0; kt < 16; ++kt) {
    const int ko = kt * 64;
#pragma unroll
    for (int i = 0; i < 4; ++i) {
      int rb = wave * 32 + i * 8;
      GLOAD_LDS16(&A[(size_t)(m0 + rb + srow) * 1024 + ko + csrc * 8],
                  &As[rb * 64]);
    }
#pragma unroll
    for (int i = 0; i < 2; ++i) {
      int rb = wave * 16 + i * 8;
      stage_rows(Wraw, (size_t)(n0 + rb), ko, srow, csrc, lane, &Bs[rb * 64], isbf);
    }
    __syncthreads();

    bf16x8 a[2][2], bfr[4][2];
#pragma unroll
    for (int mf = 0; mf < 2; ++mf) {
      const bf16* rp = &As[(wave * 32 + mf * 16 + q16) * 64];
      a[mf][0] = *(const bf16x8*)&rp[(quad ^ x7) * 8];
      a[mf][1] = *(const bf16x8*)&rp[((quad + 4) ^ x7) * 8];
    }
#pragma unroll
    for (int nt = 0; nt < 4; ++nt) {
      const bf16* rp = &Bs[(nt * 16 + q16) * 64];
      bfr[nt][0] = *(const bf16x8*)&rp[(quad ^ x7) * 8];
      bfr[nt][1] = *(const bf16x8*)&rp[((quad + 4) ^ x7) * 8];
    }
#pragma unroll
    for (int nt = 0; nt < 4; ++nt)
#pragma unroll
      for (int mf = 0; mf < 2; ++mf) {
        acc[mf][nt] = MFMA(a[mf][0], bfr[nt][0], acc[mf][nt]);
        acc[mf][nt] = MFMA(a[mf][1], bfr[nt][1], acc[mf][nt]);
      }
    __syncthreads();
  }

#pragma unroll
  for (int mf = 0; mf < 2; ++mf)
#pragma unroll
    for (int nt = 0; nt < 4; ++nt)
#pragma unroll
      for (int r = 0; r < 4; ++r) {
        size_t idx2 = (size_t)(m0 + wave * 32 + mf * 16 + quad * 4 + r) * 1024 +
                      n0 + nt * 16 + q16;
        if (isbf) ((bf16*)C)[idx2] = (bf16)acc[mf][nt][r];
        else      ((float*)C)[idx2] = acc[mf][nt][r];
      }
}

// ---------------------------------------------------------------------------
extern "C" void kernel_launch(void* const* d_in, const int* in_sizes, int n_in,
                              void* d_out, int out_size, void* d_ws, size_t ws_size,
                              hipStream_t stream) {
  bf16* qp = (bf16*)d_ws;                    // 4096*1024  (8 MB)
  bf16* kp = qp + (size_t)4096 * 1024;       // 4096*256   (2 MB)
  bf16* vt = kp + (size_t)4096 * 256;        // 4096*256   (2 MB)
  bf16* at = vt + (size_t)4096 * 256;        // 4096*1024  (8 MB)

  // x-bf16 aliases `at` (at is only written by flash, after proj consumed x).
  bf16* xb = at;
  // wq|wk|wv bf16 (3 MB) live in d_out (16 MB) -- untouched until gemm_o,
  // which overwrites d_out fully.
  bf16* wqb = (bf16*)d_out;
  bf16* wkb = wqb + (size_t)1048576;
  bf16* wvb = wkb + (size_t)262144;

  // 0) unconditional convert/copy to bf16 (device-side dtype detect)
  convert_kernel<<<2816, 256, 0, stream>>>(
      d_in[0], d_in[3], d_in[4], d_in[5], xb, wqb, d_in[1]);

  // 1) fused q/k/v projection (+ norm/rope/vtranspose)
  proj_kernel<<<768, 256, 0, stream>>>(
      xb, wqb, wkb, wvb, qp, kp, vt,
      d_in[1], d_in[2], d_in[7], d_in[8]);

  // 2) causal GQA flash attention (1 head/block, 4 blocks/CU)
  flash_kernel<<<dim3(32, 16, 2), 256, 0, stream>>>(qp, kp, vt, at);

  // 3) output projection -> d_out (W stays dtype-dual, no conversion)
  gemm_o_kernel<<<512, 256, 0, stream>>>(at, d_in[6], d_out, d_in[1]);
}

// Round 4
// 163.456 us; speedup vs baseline: 1.0607x; 1.0144x over previous
//
#include <hip/hip_runtime.h>

// GQA prefill block, MI355X gfx950. Round 18 = round 17 resubmitted verbatim
// (round-17 bench died on container acquisition, no signal). Flash v8 --
// swapped QK^T (MFMA(kb,qa) -> lane holds S[q=q16][k=quad*4+r]) so the P
// scratch roundtrip is 4x ds_write_b64 per tile instead of 32x scalar
// ds_write_b16 (was ~750 of ~1450 LDS cyc/tile/CU -- flash is LDS-pipe
// bound). Pl is per-wave [q16][k32] per kh, XOR-swizzled in 8B chunks
// (^ (q16&6), bit0 kept so the b128 read-back pair stays k-ordered); read
// directly yields the PV A-fragment. Masking re-derived for swapped
// mapping. O/l4/epilogue unchanged. Everything else identical to round 16
// (passed @165.8): convert | proj (128x64 all-gload) | flash | oproj.

typedef __bf16 bf16;
typedef __attribute__((ext_vector_type(4))) __bf16 bf16x4;
typedef __attribute__((ext_vector_type(8))) __bf16 bf16x8;
typedef __attribute__((ext_vector_type(4))) float f32x4;

#define MFMA(a, b, c) __builtin_amdgcn_mfma_f32_16x16x32_bf16((a), (b), (c), 0, 0, 0)
#define GLOAD_LDS16(g, l)                                        \
  __builtin_amdgcn_global_load_lds(                              \
      (const __attribute__((address_space(1))) void*)(g),        \
      (__attribute__((address_space(3))) void*)(l), 16, 0, 0)

__device__ __forceinline__ bool is_bf16_input(const void* cosRaw) {
  return ((const unsigned short*)cosRaw)[0] == 0x3F80;  // cos(0)=1.0 bf16
}
__device__ __forceinline__ float rdval(const void* p, int idx, bool isbf) {
  return isbf ? (float)((const bf16*)p)[idx] : ((const float*)p)[idx];
}

// stage one 8-row group (8 rows x 64 cols bf16) into LDS at ls[0..511]
// (+lane*16B by HW for bf16 path), XOR-swizzled chunks. Used by gemm_o's
// dtype-dual W staging only.
__device__ __forceinline__ void stage_rows(const void* src, size_t rowbase,
                                           int ko, int srow, int csrc,
                                           int lane, bf16* ls, bool isbf) {
  if (isbf) {
    GLOAD_LDS16(&((const bf16*)src)[(rowbase + srow) * 1024 + ko + csrc * 8], ls);
  } else {
    const float* fp = &((const float*)src)[(rowbase + srow) * 1024 + ko + csrc * 8];
    float4 f0 = *(const float4*)fp;
    float4 f1 = *(const float4*)(fp + 4);
    bf16x8 o;
    o[0] = (bf16)f0.x; o[1] = (bf16)f0.y; o[2] = (bf16)f0.z; o[3] = (bf16)f0.w;
    o[4] = (bf16)f1.x; o[5] = (bf16)f1.y; o[6] = (bf16)f1.z; o[7] = (bf16)f1.w;
    *(bf16x8*)&ls[lane * 8] = o;
  }
}

// ---------------------------------------------------------------------------
// Unconditional convert/copy -> bf16. Device-side dtype detect via cos table.
// x (4194304 elems) -> dx; wq|wk|wv (1572864 elems) -> dw contiguous.
// 8 elems/thread; chunk boundaries (8-elem units):
// x 524288 | wq 131072 | wk 32768 | wv 32768  (total 720896 = 2816 x 256).
// ---------------------------------------------------------------------------
__global__ __launch_bounds__(256) void convert_kernel(
    const void* __restrict__ x, const void* __restrict__ wq,
    const void* __restrict__ wk, const void* __restrict__ wv,
    bf16* __restrict__ dx, bf16* __restrict__ dw,
    const void* __restrict__ cosraw) {
  const bool isbf = is_bf16_input(cosraw);
  const int c = (int)blockIdx.x * 256 + (int)threadIdx.x;  // 0..720895
  const void* src;
  int off;
  bf16* dst;
  int dc;
  if (c < 524288)      { src = x;  off = c;          dst = dx; dc = c; }
  else if (c < 655360) { src = wq; off = c - 524288; dst = dw; dc = c - 524288; }
  else if (c < 688128) { src = wk; off = c - 655360; dst = dw; dc = c - 524288; }
  else                 { src = wv; off = c - 688128; dst = dw; dc = c - 524288; }
  bf16x8 o;
  if (isbf) {
    o = ((const bf16x8*)src)[off];
  } else {
    const float4* fp = (const float4*)src + (size_t)off * 2;
    float4 f0 = fp[0];
    float4 f1 = fp[1];
    o[0] = (bf16)f0.x; o[1] = (bf16)f0.y; o[2] = (bf16)f0.z; o[3] = (bf16)f0.w;
    o[4] = (bf16)f1.x; o[5] = (bf16)f1.y; o[6] = (bf16)f1.z; o[7] = (bf16)f1.w;
  }
  ((bf16x8*)dst)[dc] = o;
}

// ---------------------------------------------------------------------------
// Fused q/k/v projection. 128m x 64n tile, BK=64, single-buffered 24 KB LDS,
// grid 768 = 3 blocks/CU uniform. All staging via global_load_lds (bf16
// sources). XOR-swizzled LDS (inverse-swizzle on global source, swizzle on
// ds_read). nb 0..15 q (norm+rope+1/8 -> qp), 16..19 k (norm+rope -> kp),
// 20..23 v (block LDS transpose -> vt (B,KV,64,T)).
// ---------------------------------------------------------------------------
__global__ __launch_bounds__(256, 3) void proj_kernel(
    const bf16* __restrict__ xb, const bf16* __restrict__ wqb,
    const bf16* __restrict__ wkb, const bf16* __restrict__ wvb,
    bf16* __restrict__ qp, bf16* __restrict__ kp, bf16* __restrict__ vt,
    const void* __restrict__ cosraw, const void* __restrict__ sinraw,
    const void* __restrict__ qnraw, const void* __restrict__ knraw) {
  __shared__ bf16 As[128 * 64];  // 16 KB
  __shared__ bf16 Bs[64 * 64];   //  8 KB

  const int idx = (int)blockIdx.x;       // 0..767
  const int xcd = idx & 7;
  const int jj = idx >> 3;               // 0..95
  const int mb = (jj & 3) * 8 + xcd;     // 0..31
  const int nb = jj >> 2;                // 0..23
  const int n0 = nb * 64;
  const int m0 = mb * 128;

  const int tid = threadIdx.x;
  const int wave = tid >> 6;
  const int lane = tid & 63;
  const int q16 = lane & 15;
  const int quad = lane >> 4;
  const int srow = lane >> 3;
  const int csrc = (lane & 7) ^ srow;
  const int x7 = q16 & 7;

  const bf16* wsrc;
  int nr0;
  if (nb < 16)      { wsrc = wqb; nr0 = n0; }
  else if (nb < 20) { wsrc = wkb; nr0 = n0 - 1024; }
  else              { wsrc = wvb; nr0 = n0 - 1280; }

  f32x4 acc[2][4];
#pragma unroll
  for (int mf = 0; mf < 2; ++mf)
#pragma unroll
    for (int nt = 0; nt < 4; ++nt) acc[mf][nt] = (f32x4){0.f, 0.f, 0.f, 0.f};

  for (int kt = 0; kt < 16; ++kt) {
    const int ko = kt * 64;
#pragma unroll
    for (int i = 0; i < 4; ++i) {
      int rb = wave * 32 + i * 8;
      GLOAD_LDS16(&xb[(size_t)(m0 + rb + srow) * 1024 + ko + csrc * 8],
                  &As[rb * 64]);
    }
#pragma unroll
    for (int i = 0; i < 2; ++i) {
      int rb = wave * 16 + i * 8;
      GLOAD_LDS16(&wsrc[(size_t)(nr0 + rb + srow) * 1024 + ko + csrc * 8],
                  &Bs[rb * 64]);
    }
    __syncthreads();

    bf16x8 a[2][2], bfr[4][2];
#pragma unroll
    for (int mf = 0; mf < 2; ++mf) {
      const bf16* rp = &As[(wave * 32 + mf * 16 + q16) * 64];
      a[mf][0] = *(const bf16x8*)&rp[(quad ^ x7) * 8];
      a[mf][1] = *(const bf16x8*)&rp[((quad + 4) ^ x7) * 8];
    }
#pragma unroll
    for (int nt = 0; nt < 4; ++nt) {
      const bf16* rp = &Bs[(nt * 16 + q16) * 64];
      bfr[nt][0] = *(const bf16x8*)&rp[(quad ^ x7) * 8];
      bfr[nt][1] = *(const bf16x8*)&rp[((quad + 4) ^ x7) * 8];
    }
#pragma unroll
    for (int nt = 0; nt < 4; ++nt)
#pragma unroll
      for (int mf = 0; mf < 2; ++mf) {
        acc[mf][nt] = MFMA(a[mf][0], bfr[nt][0], acc[mf][nt]);
        acc[mf][nt] = MFMA(a[mf][1], bfr[nt][1], acc[mf][nt]);
      }
    __syncthreads();
  }

  if (nb < 20) {
    const bool isbf = is_bf16_input(cosraw);
    const void* nwp = (nb < 16) ? qnraw : knraw;
    const float osc = (nb < 16) ? 0.125f : 1.0f;
    float wd[4];
#pragma unroll
    for (int nt = 0; nt < 4; ++nt) wd[nt] = rdval(nwp, nt * 16 + q16, isbf);

#pragma unroll
    for (int mf = 0; mf < 2; ++mf) {
#pragma unroll
      for (int r = 0; r < 4; ++r) {
        float p = acc[mf][0][r] * acc[mf][0][r] + acc[mf][1][r] * acc[mf][1][r] +
                  acc[mf][2][r] * acc[mf][2][r] + acc[mf][3][r] * acc[mf][3][r];
#pragma unroll
        for (int off = 8; off >= 1; off >>= 1) p += __shfl_xor(p, off);
        float rms = rsqrtf(p * (1.0f / 64.0f) + 1e-6f);

        int row = m0 + wave * 32 + mf * 16 + quad * 4 + r;
        int t = row & 2047;
        float c0 = rdval(cosraw, t * 32 + q16, isbf);
        float c1 = rdval(cosraw, t * 32 + 16 + q16, isbf);
        float s0 = rdval(sinraw, t * 32 + q16, isbf);
        float s1 = rdval(sinraw, t * 32 + 16 + q16, isbf);

        float v0 = acc[mf][0][r] * rms * wd[0];
        float v1 = acc[mf][1][r] * rms * wd[1];
        float v2 = acc[mf][2][r] * rms * wd[2];
        float v3 = acc[mf][3][r] * rms * wd[3];

        bf16* op = (nb < 16) ? &qp[(size_t)row * 1024 + nb * 64]
                             : &kp[(size_t)row * 256 + (nb - 16) * 64];
        op[0 * 16 + q16] = (bf16)((v0 * c0 - v2 * s0) * osc);
        op[1 * 16 + q16] = (bf16)((v1 * c1 - v3 * s1) * osc);
        op[2 * 16 + q16] = (bf16)((v2 * c0 + v0 * s0) * osc);
        op[3 * 16 + q16] = (bf16)((v3 * c1 + v1 * s1) * osc);
      }
    }
  } else {
    const int vh = nb - 20;
    const int b = m0 >> 11;
    const int tbase = m0 & 2047;
#pragma unroll
    for (int mf = 0; mf < 2; ++mf)
#pragma unroll
      for (int nt = 0; nt < 4; ++nt)
#pragma unroll
        for (int r = 0; r < 4; ++r)
          As[(wave * 32 + mf * 16 + quad * 4 + r) * 64 + nt * 16 + q16] =
              (bf16)acc[mf][nt][r];
    __syncthreads();
#pragma unroll
    for (int rep = 0; rep < 4; ++rep) {
      int c = tid + 256 * rep;      // 0..1023
      int d = c >> 4;               // 0..63
      int t8 = (c & 15) * 8;        // 0..120
      bf16x8 pk;
#pragma unroll
      for (int j = 0; j < 8; ++j) pk[j] = As[(t8 + j) * 64 + d];
      *(bf16x8*)&vt[(((size_t)(b * 4 + vh)) * 64 + d) * 2048 + tbase + t8] = pk;
    }
  }
}

// ---------------------------------------------------------------------------
// Flash attention v8: swapped QK^T. 1 head/block, grid (32,16,2) = 1024 =
// 4 blocks/CU. LDS 36 KB: K/V dbuf (16+16) + per-wave [q16][k32] P scratch
// (4 KB). Lane holds S[q=q16][k=kt*16+quad*4+r] -> P write = 1 b64/kt,
// read-back b128 = PV A-fragment directly. Fixed-max softmax exp(S-9);
// l via ones-MFMA. qblk pairing -> 66 tile-units/CU uniform.
// ---------------------------------------------------------------------------
__global__ __launch_bounds__(256, 4) void flash_kernel(
    const bf16* __restrict__ qp, const bf16* __restrict__ kp,
    const bf16* __restrict__ vt, bf16* __restrict__ attn) {
  const int qblk = blockIdx.z ? 31 - (int)blockIdx.x : (int)blockIdx.x;
  const int h = blockIdx.y;
  const int b = blockIdx.z;
  const int kvh = h >> 2;
  const int tid = threadIdx.x;
  const int wave = tid >> 6;
  const int lane = tid & 63;
  const int q16 = lane & 15;
  const int quad = lane >> 4;
  const int r7 = q16 & 7;
  const int t0 = qblk * 64 + wave * 16;

  __shared__ bf16 Ks[2][64 * 64];   // 16 KB
  __shared__ bf16 Vs[2][64 * 64];   // 16 KB
  __shared__ bf16 Pl[4][16 * 32];   //  4 KB, per-wave, [q16][k32] 8B-swizzled

  const bf16* qrow = qp + (((size_t)(b * 2048 + t0 + q16)) * 16 + h) * 64;
  bf16x8 qa0 = *(const bf16x8*)(qrow + quad * 8);
  bf16x8 qa1 = *(const bf16x8*)(qrow + 32 + quad * 8);

  bf16x8 ones;
#pragma unroll
  for (int j = 0; j < 8; ++j) ones[j] = (bf16)1.0f;

  f32x4 O[4], l4;
#pragma unroll
  for (int nt = 0; nt < 4; ++nt) O[nt] = (f32x4){0.f, 0.f, 0.f, 0.f};
  l4 = (f32x4){0.f, 0.f, 0.f, 0.f};

  const int ntile = qblk + 1;

  bf16x8 kr[2], vr[2];
  const int cr = tid * 2;
  const int krow = cr >> 3;
  const size_t kgbase = (((size_t)(b * 2048) + krow) * 4 + kvh) * 64;
  const size_t vgbase = ((size_t)(b * 4 + kvh) * 64 + krow) * 2048;

  auto gload = [&](int tk) {
#pragma unroll
    for (int rep = 0; rep < 2; ++rep) {
      int ch = (cr + rep) & 7;
      kr[rep] = *(const bf16x8*)&kp[kgbase + (size_t)(tk * 64) * 256 + ch * 8];
      vr[rep] = *(const bf16x8*)&vt[vgbase + tk * 64 + ch * 8];
    }
  };
  auto swrite = [&](int bb) {
#pragma unroll
    for (int rep = 0; rep < 2; ++rep) {
      int ch = (cr + rep) & 7;
      int pos = (ch ^ (krow & 7)) * 8;
      *(bf16x8*)&Ks[bb][krow * 64 + pos] = kr[rep];
      *(bf16x8*)&Vs[bb][krow * 64 + pos] = vr[rep];
    }
  };

  gload(0);

  for (int t = 0; t < ntile; ++t) {
    const int bb = t & 1;
    const int kbase = t * 64;
    swrite(bb);
    __syncthreads();
    if (t + 1 < ntile) gload(t + 1);

    // S^T fragments: MFMA(K, Q) -> s[kt][r] = S[q=t0+q16][k=kbase+kt*16+quad*4+r]
    f32x4 s[4];
#pragma unroll
    for (int kt = 0; kt < 4; ++kt) {
      const bf16* kr0 = &Ks[bb][(kt * 16 + q16) * 64];
      bf16x8 kb0 = *(const bf16x8*)&kr0[(quad ^ r7) * 8];
      bf16x8 kb1 = *(const bf16x8*)&kr0[((quad + 4) ^ r7) * 8];
      f32x4 z = (f32x4){0.f, 0.f, 0.f, 0.f};
      z = MFMA(kb0, qa0, z);
      z = MFMA(kb1, qa1, z);
      s[kt] = z;
    }

    if (kbase + 63 > t0) {
      const int q = t0 + q16;
#pragma unroll
      for (int kt = 0; kt < 4; ++kt) {
        int jt = kbase + kt * 16 + quad * 4;
#pragma unroll
        for (int r = 0; r < 4; ++r)
          if (jt + r > q) s[kt][r] = -1e30f;
      }
    }

#pragma unroll
    for (int kt = 0; kt < 4; ++kt)
#pragma unroll
      for (int r = 0; r < 4; ++r) s[kt][r] = __expf(s[kt][r] - 9.0f);

    // P roundtrip: per kh, two packed b64 writes ([q16][k32], 8B chunks
    // XOR'd by q16&6, bit0 kept), one b128 read = PV A-fragment. + PV.
#pragma unroll
    for (int kh = 0; kh < 2; ++kh) {
#pragma unroll
      for (int ct = 0; ct < 2; ++ct) {
        const int kt = kh * 2 + ct;
        bf16x4 pk;
#pragma unroll
        for (int r = 0; r < 4; ++r) pk[r] = (bf16)s[kt][r];
        *(bf16x4*)&Pl[wave][q16 * 32 + ((ct * 4 + quad) ^ (q16 & 6)) * 4] = pk;
      }
      bf16x8 pa = *(const bf16x8*)&Pl[wave][q16 * 32 + ((quad * 2) ^ (q16 & 6)) * 4];
#pragma unroll
      for (int nt = 0; nt < 4; ++nt) {
        const bf16* vr0 = &Vs[bb][(nt * 16 + q16) * 64];
        bf16x8 vb = *(const bf16x8*)&vr0[((kh * 4 + quad) ^ r7) * 8];
        O[nt] = MFMA(pa, vb, O[nt]);
      }
      l4 = MFMA(pa, ones, l4);
    }
  }

  float inv[4];
#pragma unroll
  for (int r = 0; r < 4; ++r) inv[r] = 1.0f / l4[r];
#pragma unroll
  for (int nt = 0; nt < 4; ++nt)
#pragma unroll
    for (int r = 0; r < 4; ++r) {
      size_t o = (((size_t)(b * 2048 + t0 + quad * 4 + r)) * 16 + h) * 64 +
                 nt * 16 + q16;
      attn[o] = (bf16)(O[nt][r] * inv[r]);
    }
}

// ---------------------------------------------------------------------------
// o-projection: 128m x 64n BK=64 single-buffered, grid 512 = 2 blocks/CU
// uniform, XCD swizzle. A (bf16) via global_load_lds; W dtype-dual via
// stage_rows. Output dtype per detected dtype.
// ---------------------------------------------------------------------------
__global__ __launch_bounds__(256, 2) void gemm_o_kernel(
    const bf16* __restrict__ A, const void* __restrict__ Wraw,
    void* __restrict__ C, const void* __restrict__ cosraw) {
  __shared__ bf16 As[128 * 64];  // 16 KB
  __shared__ bf16 Bs[64 * 64];   //  8 KB

  const int idx = (int)blockIdx.x;       // 0..511
  const int xcd = idx & 7;
  const int jj = idx >> 3;               // 0..63
  const int mb = (jj & 3) * 8 + xcd;     // 0..31
  const int nb = jj >> 2;                // 0..15
  const int n0 = nb * 64;
  const int m0 = mb * 128;

  const int tid = threadIdx.x;
  const int wave = tid >> 6;
  const int lane = tid & 63;
  const int q16 = lane & 15;
  const int quad = lane >> 4;
  const int srow = lane >> 3;
  const int csrc = (lane & 7) ^ srow;
  const int x7 = q16 & 7;
  const bool isbf = is_bf16_input(cosraw);

  f32x4 acc[2][4];
#pragma unroll
  for (int mf = 0; mf < 2; ++mf)
#pragma unroll
    for (int nt = 0; nt < 4; ++nt) acc[mf][nt] = (f32x4){0.f, 0.f, 0.f, 0.f};

  for (int kt = 0; kt < 16; ++kt) {
    const int ko = kt * 64;
#pragma unroll
    for (int i = 0; i < 4; ++i) {
      int rb = wave * 32 + i * 8;
      GLOAD_LDS16(&A[(size_t)(m0 + rb + srow) * 1024 + ko + csrc * 8],
                  &As[rb * 64]);
    }
#pragma unroll
    for (int i = 0; i < 2; ++i) {
      int rb = wave * 16 + i * 8;
      stage_rows(Wraw, (size_t)(n0 + rb), ko, srow, csrc, lane, &Bs[rb * 64], isbf);
    }
    __syncthreads();

    bf16x8 a[2][2], bfr[4][2];
#pragma unroll
    for (int mf = 0; mf < 2; ++mf) {
      const bf16* rp = &As[(wave * 32 + mf * 16 + q16) * 64];
      a[mf][0] = *(const bf16x8*)&rp[(quad ^ x7) * 8];
      a[mf][1] = *(const bf16x8*)&rp[((quad + 4) ^ x7) * 8];
    }
#pragma unroll
    for (int nt = 0; nt < 4; ++nt) {
      const bf16* rp = &Bs[(nt * 16 + q16) * 64];
      bfr[nt][0] = *(const bf16x8*)&rp[(quad ^ x7) * 8];
      bfr[nt][1] = *(const bf16x8*)&rp[((quad + 4) ^ x7) * 8];
    }
#pragma unroll
    for (int nt = 0; nt < 4; ++nt)
#pragma unroll
      for (int mf = 0; mf < 2; ++mf) {
        acc[mf][nt] = MFMA(a[mf][0], bfr[nt][0], acc[mf][nt]);
        acc[mf][nt] = MFMA(a[mf][1], bfr[nt][1], acc[mf][nt]);
      }
    __syncthreads();
  }

#pragma unroll
  for (int mf = 0; mf < 2; ++mf)
#pragma unroll
    for (int nt = 0; nt < 4; ++nt)
#pragma unroll
      for (int r = 0; r < 4; ++r) {
        size_t idx2 = (size_t)(m0 + wave * 32 + mf * 16 + quad * 4 + r) * 1024 +
                      n0 + nt * 16 + q16;
        if (isbf) ((bf16*)C)[idx2] = (bf16)acc[mf][nt][r];
        else      ((float*)C)[idx2] = acc[mf][nt][r];
      }
}

// ---------------------------------------------------------------------------
extern "C" void kernel_launch(void* const* d_in, const int* in_sizes, int n_in,
                              void* d_out, int out_size, void* d_ws, size_t ws_size,
                              hipStream_t stream) {
  bf16* qp = (bf16*)d_ws;                    // 4096*1024  (8 MB)
  bf16* kp = qp + (size_t)4096 * 1024;       // 4096*256   (2 MB)
  bf16* vt = kp + (size_t)4096 * 256;        // 4096*256   (2 MB)
  bf16* at = vt + (size_t)4096 * 256;        // 4096*1024  (8 MB)

  // x-bf16 aliases `at` (at is only written by flash, after proj consumed x).
  bf16* xb = at;
  // wq|wk|wv bf16 (3 MB) live in d_out (16 MB) -- untouched until gemm_o,
  // which overwrites d_out fully.
  bf16* wqb = (bf16*)d_out;
  bf16* wkb = wqb + (size_t)1048576;
  bf16* wvb = wkb + (size_t)262144;

  // 0) unconditional convert/copy to bf16 (device-side dtype detect)
  convert_kernel<<<2816, 256, 0, stream>>>(
      d_in[0], d_in[3], d_in[4], d_in[5], xb, wqb, d_in[1]);

  // 1) fused q/k/v projection (+ norm/rope/vtranspose)
  proj_kernel<<<768, 256, 0, stream>>>(
      xb, wqb, wkb, wvb, qp, kp, vt,
      d_in[1], d_in[2], d_in[7], d_in[8]);

  // 2) causal GQA flash attention (1 head/block, 4 blocks/CU)
  flash_kernel<<<dim3(32, 16, 2), 256, 0, stream>>>(qp, kp, vt, at);

  // 3) output projection -> d_out (W stays dtype-dual, no conversion)
  gemm_o_kernel<<<512, 256, 0, stream>>>(at, d_in[6], d_out, d_in[1]);
}

// Round 5
// 154.835 us; speedup vs baseline: 1.1197x; 1.0557x over previous
//
#include <hip/hip_runtime.h>

// GQA prefill block, MI355X gfx950. Round 19: oproj occupancy fix. Evidence:
// fill WRITE_SIZE=268MB -> ws ~256MB and the 42us fill is inside the timed
// iteration; back-solving deltas gives flash~40, oproj~40. oproj at grid 512
// = 2 blocks/CU is the m132 regression regime and W was fp32-staged. Now:
// wo joins the convert pass (all bf16 copies in dedicated d_ws regions,
// 33 MB total, no aliasing), oproj reverts to 64x64 grid 1024 = 4 blocks/CU
// with pure-bf16 global_load_lds staging for A and W. proj/flash unchanged
// from round 18 (passed @163.5). 4 dispatches: convert | proj | flash | oproj.

typedef __bf16 bf16;
typedef __attribute__((ext_vector_type(4))) __bf16 bf16x4;
typedef __attribute__((ext_vector_type(8))) __bf16 bf16x8;
typedef __attribute__((ext_vector_type(4))) float f32x4;

#define MFMA(a, b, c) __builtin_amdgcn_mfma_f32_16x16x32_bf16((a), (b), (c), 0, 0, 0)
#define GLOAD_LDS16(g, l)                                        \
  __builtin_amdgcn_global_load_lds(                              \
      (const __attribute__((address_space(1))) void*)(g),        \
      (__attribute__((address_space(3))) void*)(l), 16, 0, 0)

__device__ __forceinline__ bool is_bf16_input(const void* cosRaw) {
  return ((const unsigned short*)cosRaw)[0] == 0x3F80;  // cos(0)=1.0 bf16
}
__device__ __forceinline__ float rdval(const void* p, int idx, bool isbf) {
  return isbf ? (float)((const bf16*)p)[idx] : ((const float*)p)[idx];
}

// ---------------------------------------------------------------------------
// Unconditional convert/copy -> bf16. Device-side dtype detect via cos table.
// x (4194304 el) -> dx; wq|wk|wv|wo (2621440 el) -> dw contiguous.
// 8 el/thread; chunk boundaries (8-el units):
// x 524288 | wq 131072 | wk 32768 | wv 32768 | wo 131072
// total 851968 = 3328 x 256. Weight dst chunk = c - 524288.
// ---------------------------------------------------------------------------
__global__ __launch_bounds__(256) void convert_kernel(
    const void* __restrict__ x, const void* __restrict__ wq,
    const void* __restrict__ wk, const void* __restrict__ wv,
    const void* __restrict__ wo, bf16* __restrict__ dx,
    bf16* __restrict__ dw, const void* __restrict__ cosraw) {
  const bool isbf = is_bf16_input(cosraw);
  const int c = (int)blockIdx.x * 256 + (int)threadIdx.x;  // 0..851967
  const void* src;
  int off;
  bf16* dst;
  int dc;
  if (c < 524288)      { src = x;  off = c;          dst = dx; dc = c; }
  else if (c < 655360) { src = wq; off = c - 524288; dst = dw; dc = c - 524288; }
  else if (c < 688128) { src = wk; off = c - 655360; dst = dw; dc = c - 524288; }
  else if (c < 720896) { src = wv; off = c - 688128; dst = dw; dc = c - 524288; }
  else                 { src = wo; off = c - 720896; dst = dw; dc = c - 524288; }
  bf16x8 o;
  if (isbf) {
    o = ((const bf16x8*)src)[off];
  } else {
    const float4* fp = (const float4*)src + (size_t)off * 2;
    float4 f0 = fp[0];
    float4 f1 = fp[1];
    o[0] = (bf16)f0.x; o[1] = (bf16)f0.y; o[2] = (bf16)f0.z; o[3] = (bf16)f0.w;
    o[4] = (bf16)f1.x; o[5] = (bf16)f1.y; o[6] = (bf16)f1.z; o[7] = (bf16)f1.w;
  }
  ((bf16x8*)dst)[dc] = o;
}

// ---------------------------------------------------------------------------
// Fused q/k/v projection (unchanged from round 18). 128m x 64n tile, BK=64,
// single-buffered 24 KB LDS, grid 768 = 3 blocks/CU uniform. All staging via
// global_load_lds (bf16 sources). XOR-swizzled LDS. nb 0..15 q
// (norm+rope+1/8 -> qp), 16..19 k (norm+rope -> kp), 20..23 v
// (block LDS transpose -> vt (B,KV,64,T)).
// ---------------------------------------------------------------------------
__global__ __launch_bounds__(256, 3) void proj_kernel(
    const bf16* __restrict__ xb, const bf16* __restrict__ wqb,
    const bf16* __restrict__ wkb, const bf16* __restrict__ wvb,
    bf16* __restrict__ qp, bf16* __restrict__ kp, bf16* __restrict__ vt,
    const void* __restrict__ cosraw, const void* __restrict__ sinraw,
    const void* __restrict__ qnraw, const void* __restrict__ knraw) {
  __shared__ bf16 As[128 * 64];  // 16 KB
  __shared__ bf16 Bs[64 * 64];   //  8 KB

  const int idx = (int)blockIdx.x;       // 0..767
  const int xcd = idx & 7;
  const int jj = idx >> 3;               // 0..95
  const int mb = (jj & 3) * 8 + xcd;     // 0..31
  const int nb = jj >> 2;                // 0..23
  const int n0 = nb * 64;
  const int m0 = mb * 128;

  const int tid = threadIdx.x;
  const int wave = tid >> 6;
  const int lane = tid & 63;
  const int q16 = lane & 15;
  const int quad = lane >> 4;
  const int srow = lane >> 3;
  const int csrc = (lane & 7) ^ srow;
  const int x7 = q16 & 7;

  const bf16* wsrc;
  int nr0;
  if (nb < 16)      { wsrc = wqb; nr0 = n0; }
  else if (nb < 20) { wsrc = wkb; nr0 = n0 - 1024; }
  else              { wsrc = wvb; nr0 = n0 - 1280; }

  f32x4 acc[2][4];
#pragma unroll
  for (int mf = 0; mf < 2; ++mf)
#pragma unroll
    for (int nt = 0; nt < 4; ++nt) acc[mf][nt] = (f32x4){0.f, 0.f, 0.f, 0.f};

  for (int kt = 0; kt < 16; ++kt) {
    const int ko = kt * 64;
#pragma unroll
    for (int i = 0; i < 4; ++i) {
      int rb = wave * 32 + i * 8;
      GLOAD_LDS16(&xb[(size_t)(m0 + rb + srow) * 1024 + ko + csrc * 8],
                  &As[rb * 64]);
    }
#pragma unroll
    for (int i = 0; i < 2; ++i) {
      int rb = wave * 16 + i * 8;
      GLOAD_LDS16(&wsrc[(size_t)(nr0 + rb + srow) * 1024 + ko + csrc * 8],
                  &Bs[rb * 64]);
    }
    __syncthreads();

    bf16x8 a[2][2], bfr[4][2];
#pragma unroll
    for (int mf = 0; mf < 2; ++mf) {
      const bf16* rp = &As[(wave * 32 + mf * 16 + q16) * 64];
      a[mf][0] = *(const bf16x8*)&rp[(quad ^ x7) * 8];
      a[mf][1] = *(const bf16x8*)&rp[((quad + 4) ^ x7) * 8];
    }
#pragma unroll
    for (int nt = 0; nt < 4; ++nt) {
      const bf16* rp = &Bs[(nt * 16 + q16) * 64];
      bfr[nt][0] = *(const bf16x8*)&rp[(quad ^ x7) * 8];
      bfr[nt][1] = *(const bf16x8*)&rp[((quad + 4) ^ x7) * 8];
    }
#pragma unroll
    for (int nt = 0; nt < 4; ++nt)
#pragma unroll
      for (int mf = 0; mf < 2; ++mf) {
        acc[mf][nt] = MFMA(a[mf][0], bfr[nt][0], acc[mf][nt]);
        acc[mf][nt] = MFMA(a[mf][1], bfr[nt][1], acc[mf][nt]);
      }
    __syncthreads();
  }

  if (nb < 20) {
    const bool isbf = is_bf16_input(cosraw);
    const void* nwp = (nb < 16) ? qnraw : knraw;
    const float osc = (nb < 16) ? 0.125f : 1.0f;
    float wd[4];
#pragma unroll
    for (int nt = 0; nt < 4; ++nt) wd[nt] = rdval(nwp, nt * 16 + q16, isbf);

#pragma unroll
    for (int mf = 0; mf < 2; ++mf) {
#pragma unroll
      for (int r = 0; r < 4; ++r) {
        float p = acc[mf][0][r] * acc[mf][0][r] + acc[mf][1][r] * acc[mf][1][r] +
                  acc[mf][2][r] * acc[mf][2][r] + acc[mf][3][r] * acc[mf][3][r];
#pragma unroll
        for (int off = 8; off >= 1; off >>= 1) p += __shfl_xor(p, off);
        float rms = rsqrtf(p * (1.0f / 64.0f) + 1e-6f);

        int row = m0 + wave * 32 + mf * 16 + quad * 4 + r;
        int t = row & 2047;
        float c0 = rdval(cosraw, t * 32 + q16, isbf);
        float c1 = rdval(cosraw, t * 32 + 16 + q16, isbf);
        float s0 = rdval(sinraw, t * 32 + q16, isbf);
        float s1 = rdval(sinraw, t * 32 + 16 + q16, isbf);

        float v0 = acc[mf][0][r] * rms * wd[0];
        float v1 = acc[mf][1][r] * rms * wd[1];
        float v2 = acc[mf][2][r] * rms * wd[2];
        float v3 = acc[mf][3][r] * rms * wd[3];

        bf16* op = (nb < 16) ? &qp[(size_t)row * 1024 + nb * 64]
                             : &kp[(size_t)row * 256 + (nb - 16) * 64];
        op[0 * 16 + q16] = (bf16)((v0 * c0 - v2 * s0) * osc);
        op[1 * 16 + q16] = (bf16)((v1 * c1 - v3 * s1) * osc);
        op[2 * 16 + q16] = (bf16)((v2 * c0 + v0 * s0) * osc);
        op[3 * 16 + q16] = (bf16)((v3 * c1 + v1 * s1) * osc);
      }
    }
  } else {
    const int vh = nb - 20;
    const int b = m0 >> 11;
    const int tbase = m0 & 2047;
#pragma unroll
    for (int mf = 0; mf < 2; ++mf)
#pragma unroll
      for (int nt = 0; nt < 4; ++nt)
#pragma unroll
        for (int r = 0; r < 4; ++r)
          As[(wave * 32 + mf * 16 + quad * 4 + r) * 64 + nt * 16 + q16] =
              (bf16)acc[mf][nt][r];
    __syncthreads();
#pragma unroll
    for (int rep = 0; rep < 4; ++rep) {
      int c = tid + 256 * rep;      // 0..1023
      int d = c >> 4;               // 0..63
      int t8 = (c & 15) * 8;        // 0..120
      bf16x8 pk;
#pragma unroll
      for (int j = 0; j < 8; ++j) pk[j] = As[(t8 + j) * 64 + d];
      *(bf16x8*)&vt[(((size_t)(b * 4 + vh)) * 64 + d) * 2048 + tbase + t8] = pk;
    }
  }
}

// ---------------------------------------------------------------------------
// Flash attention v8 (unchanged from round 18): swapped QK^T. 1 head/block,
// grid (32,16,2) = 1024 = 4 blocks/CU. LDS 36 KB. Lane holds
// S[q=q16][k=kt*16+quad*4+r] -> P write = 1 b64/kt, b128 read-back = PV
// A-fragment. Fixed-max softmax exp(S-9); l via ones-MFMA.
// ---------------------------------------------------------------------------
__global__ __launch_bounds__(256, 4) void flash_kernel(
    const bf16* __restrict__ qp, const bf16* __restrict__ kp,
    const bf16* __restrict__ vt, bf16* __restrict__ attn) {
  const int qblk = blockIdx.z ? 31 - (int)blockIdx.x : (int)blockIdx.x;
  const int h = blockIdx.y;
  const int b = blockIdx.z;
  const int kvh = h >> 2;
  const int tid = threadIdx.x;
  const int wave = tid >> 6;
  const int lane = tid & 63;
  const int q16 = lane & 15;
  const int quad = lane >> 4;
  const int r7 = q16 & 7;
  const int t0 = qblk * 64 + wave * 16;

  __shared__ bf16 Ks[2][64 * 64];   // 16 KB
  __shared__ bf16 Vs[2][64 * 64];   // 16 KB
  __shared__ bf16 Pl[4][16 * 32];   //  4 KB, per-wave, [q16][k32] 8B-swizzled

  const bf16* qrow = qp + (((size_t)(b * 2048 + t0 + q16)) * 16 + h) * 64;
  bf16x8 qa0 = *(const bf16x8*)(qrow + quad * 8);
  bf16x8 qa1 = *(const bf16x8*)(qrow + 32 + quad * 8);

  bf16x8 ones;
#pragma unroll
  for (int j = 0; j < 8; ++j) ones[j] = (bf16)1.0f;

  f32x4 O[4], l4;
#pragma unroll
  for (int nt = 0; nt < 4; ++nt) O[nt] = (f32x4){0.f, 0.f, 0.f, 0.f};
  l4 = (f32x4){0.f, 0.f, 0.f, 0.f};

  const int ntile = qblk + 1;

  bf16x8 kr[2], vr[2];
  const int cr = tid * 2;
  const int krow = cr >> 3;
  const size_t kgbase = (((size_t)(b * 2048) + krow) * 4 + kvh) * 64;
  const size_t vgbase = ((size_t)(b * 4 + kvh) * 64 + krow) * 2048;

  auto gload = [&](int tk) {
#pragma unroll
    for (int rep = 0; rep < 2; ++rep) {
      int ch = (cr + rep) & 7;
      kr[rep] = *(const bf16x8*)&kp[kgbase + (size_t)(tk * 64) * 256 + ch * 8];
      vr[rep] = *(const bf16x8*)&vt[vgbase + tk * 64 + ch * 8];
    }
  };
  auto swrite = [&](int bb) {
#pragma unroll
    for (int rep = 0; rep < 2; ++rep) {
      int ch = (cr + rep) & 7;
      int pos = (ch ^ (krow & 7)) * 8;
      *(bf16x8*)&Ks[bb][krow * 64 + pos] = kr[rep];
      *(bf16x8*)&Vs[bb][krow * 64 + pos] = vr[rep];
    }
  };

  gload(0);

  for (int t = 0; t < ntile; ++t) {
    const int bb = t & 1;
    const int kbase = t * 64;
    swrite(bb);
    __syncthreads();
    if (t + 1 < ntile) gload(t + 1);

    // S^T fragments: MFMA(K, Q) -> s[kt][r] = S[q=t0+q16][k=kbase+kt*16+quad*4+r]
    f32x4 s[4];
#pragma unroll
    for (int kt = 0; kt < 4; ++kt) {
      const bf16* kr0 = &Ks[bb][(kt * 16 + q16) * 64];
      bf16x8 kb0 = *(const bf16x8*)&kr0[(quad ^ r7) * 8];
      bf16x8 kb1 = *(const bf16x8*)&kr0[((quad + 4) ^ r7) * 8];
      f32x4 z = (f32x4){0.f, 0.f, 0.f, 0.f};
      z = MFMA(kb0, qa0, z);
      z = MFMA(kb1, qa1, z);
      s[kt] = z;
    }

    if (kbase + 63 > t0) {
      const int q = t0 + q16;
#pragma unroll
      for (int kt = 0; kt < 4; ++kt) {
        int jt = kbase + kt * 16 + quad * 4;
#pragma unroll
        for (int r = 0; r < 4; ++r)
          if (jt + r > q) s[kt][r] = -1e30f;
      }
    }

#pragma unroll
    for (int kt = 0; kt < 4; ++kt)
#pragma unroll
      for (int r = 0; r < 4; ++r) s[kt][r] = __expf(s[kt][r] - 9.0f);

    // P roundtrip: per kh, two packed b64 writes ([q16][k32], 8B chunks
    // XOR'd by q16&6, bit0 kept), one b128 read = PV A-fragment. + PV.
#pragma unroll
    for (int kh = 0; kh < 2; ++kh) {
#pragma unroll
      for (int ct = 0; ct < 2; ++ct) {
        const int kt = kh * 2 + ct;
        bf16x4 pk;
#pragma unroll
        for (int r = 0; r < 4; ++r) pk[r] = (bf16)s[kt][r];
        *(bf16x4*)&Pl[wave][q16 * 32 + ((ct * 4 + quad) ^ (q16 & 6)) * 4] = pk;
      }
      bf16x8 pa = *(const bf16x8*)&Pl[wave][q16 * 32 + ((quad * 2) ^ (q16 & 6)) * 4];
#pragma unroll
      for (int nt = 0; nt < 4; ++nt) {
        const bf16* vr0 = &Vs[bb][(nt * 16 + q16) * 64];
        bf16x8 vb = *(const bf16x8*)&vr0[((kh * 4 + quad) ^ r7) * 8];
        O[nt] = MFMA(pa, vb, O[nt]);
      }
      l4 = MFMA(pa, ones, l4);
    }
  }

  float inv[4];
#pragma unroll
  for (int r = 0; r < 4; ++r) inv[r] = 1.0f / l4[r];
#pragma unroll
  for (int nt = 0; nt < 4; ++nt)
#pragma unroll
    for (int r = 0; r < 4; ++r) {
      size_t o = (((size_t)(b * 2048 + t0 + quad * 4 + r)) * 16 + h) * 64 +
                 nt * 16 + q16;
      attn[o] = (bf16)(O[nt][r] * inv[r]);
    }
}

// ---------------------------------------------------------------------------
// o-projection: 64m x 64n BK=64 single-buffered 16 KB LDS, grid 1024 =
// 4 blocks/CU uniform (2/CU at 128-tile was the m132 regression regime),
// XCD swizzle. A and W (both bf16) via global_load_lds -- zero staging VALU.
// Output dtype per detected dtype.
// ---------------------------------------------------------------------------
__global__ __launch_bounds__(256, 6) void gemm_o_kernel(
    const bf16* __restrict__ A, const bf16* __restrict__ W,
    void* __restrict__ C, const void* __restrict__ cosraw) {
  __shared__ bf16 As[64 * 64];   // 8 KB
  __shared__ bf16 Bs[64 * 64];   // 8 KB

  const int idx = (int)blockIdx.x;     // 0..1023
  const int xcd = idx & 7;
  const int jj = idx >> 3;             // 0..127
  const int mb = (jj & 7) * 8 + xcd;   // 0..63
  const int nb = jj >> 3;              // 0..15
  const int n0 = nb * 64;
  const int m0 = mb * 64;

  const int tid = threadIdx.x;
  const int wave = tid >> 6;
  const int lane = tid & 63;
  const int q16 = lane & 15;
  const int quad = lane >> 4;
  const int srow = lane >> 3;
  const int csrc = (lane & 7) ^ srow;
  const int wm = wave * 16;
  const int x7 = q16 & 7;
  const bool isbf = is_bf16_input(cosraw);

  f32x4 acc[4];
#pragma unroll
  for (int nt = 0; nt < 4; ++nt) acc[nt] = (f32x4){0.f, 0.f, 0.f, 0.f};

  for (int kt = 0; kt < 16; ++kt) {
    const int ko = kt * 64;
#pragma unroll
    for (int i = 0; i < 2; ++i) {
      int rb = wave * 16 + i * 8;
      GLOAD_LDS16(&A[(size_t)(m0 + rb + srow) * 1024 + ko + csrc * 8],
                  &As[rb * 64]);
      GLOAD_LDS16(&W[(size_t)(n0 + rb + srow) * 1024 + ko + csrc * 8],
                  &Bs[rb * 64]);
    }
    __syncthreads();

    bf16x8 a0, a1, bfr[4][2];
    {
      const bf16* rp = &As[(wm + q16) * 64];
      a0 = *(const bf16x8*)&rp[(quad ^ x7) * 8];
      a1 = *(const bf16x8*)&rp[((quad + 4) ^ x7) * 8];
    }
#pragma unroll
    for (int nt = 0; nt < 4; ++nt) {
      const bf16* rp = &Bs[(nt * 16 + q16) * 64];
      bfr[nt][0] = *(const bf16x8*)&rp[(quad ^ x7) * 8];
      bfr[nt][1] = *(const bf16x8*)&rp[((quad + 4) ^ x7) * 8];
    }
#pragma unroll
    for (int nt = 0; nt < 4; ++nt) {
      acc[nt] = MFMA(a0, bfr[nt][0], acc[nt]);
      acc[nt] = MFMA(a1, bfr[nt][1], acc[nt]);
    }
    __syncthreads();
  }

#pragma unroll
  for (int nt = 0; nt < 4; ++nt)
#pragma unroll
    for (int r = 0; r < 4; ++r) {
      size_t idx2 = (size_t)(m0 + wm + quad * 4 + r) * 1024 + n0 + nt * 16 + q16;
      if (isbf) ((bf16*)C)[idx2] = (bf16)acc[nt][r];
      else      ((float*)C)[idx2] = acc[nt][r];
    }
}

// ---------------------------------------------------------------------------
extern "C" void kernel_launch(void* const* d_in, const int* in_sizes, int n_in,
                              void* d_out, int out_size, void* d_ws, size_t ws_size,
                              hipStream_t stream) {
  // d_ws layout (bf16 elems). fill WRITE_SIZE evidence: ws ~256 MB; use 33 MB.
  bf16* qp = (bf16*)d_ws;                      // 4194304 el  (8 MB)
  bf16* kp = qp + (size_t)4194304;             // 1048576 el  (2 MB)
  bf16* vt = kp + (size_t)1048576;             // 1048576 el  (2 MB)
  bf16* at = vt + (size_t)1048576;             // 4194304 el  (8 MB)
  bf16* xb = at + (size_t)4194304;             // 4194304 el  (8 MB)
  bf16* dw = xb + (size_t)4194304;             // 2621440 el  (5 MB) wq|wk|wv|wo

  bf16* wqb = dw;
  bf16* wkb = dw + (size_t)1048576;
  bf16* wvb = dw + (size_t)1310720;
  bf16* wob = dw + (size_t)1572864;

  // 0) unconditional convert/copy to bf16 (device-side dtype detect)
  convert_kernel<<<3328, 256, 0, stream>>>(
      d_in[0], d_in[3], d_in[4], d_in[5], d_in[6], xb, dw, d_in[1]);

  // 1) fused q/k/v projection (+ norm/rope/vtranspose)
  proj_kernel<<<768, 256, 0, stream>>>(
      xb, wqb, wkb, wvb, qp, kp, vt,
      d_in[1], d_in[2], d_in[7], d_in[8]);

  // 2) causal GQA flash attention (1 head/block, 4 blocks/CU)
  flash_kernel<<<dim3(32, 16, 2), 256, 0, stream>>>(qp, kp, vt, at);

  // 3) output projection -> d_out (all-bf16 gload staging)
  gemm_o_kernel<<<1024, 256, 0, stream>>>(at, wob, d_out, d_in[1]);
}